// Round 5
// baseline (446.352 us; speedup 1.0000x reference)
//
#include <hip/hip_runtime.h>
#include <stdint.h>

#define B_ 8
#define S_ 1024
#define D_ 1024
#define H_ 2048
#define E_ 8
#define DN_ 256

typedef unsigned char u8;
typedef unsigned int u32;
typedef float f32x4 __attribute__((ext_vector_type(4)));
typedef long long ll;

// fp8 e4m3 (OCP on gfx950) converts
__device__ __forceinline__ u8 f2f8(float f) {
  return (u8)(__builtin_amdgcn_cvt_pk_fp8_f32(f, f, 0, false) & 0xff);
}
__device__ __forceinline__ u32 pk4f8(float a, float b, float c, float d) {
  int w = __builtin_amdgcn_cvt_pk_fp8_f32(a, b, 0, false);
  w = __builtin_amdgcn_cvt_pk_fp8_f32(c, d, w, true);
  return (u32)w;
}

// async global->LDS, 16B per lane. LDS dest is wave-uniform base; HW adds lane*16.
__device__ __forceinline__ void gll16(const void* g, void* l) {
  __builtin_amdgcn_global_load_lds(
      (__attribute__((address_space(1))) void*)g,
      (__attribute__((address_space(3))) void*)l, 16, 0, 0);
}

// ---------------- merged prep: router + cast x + transpose/cast weights ----------------
// 256-row x 64-col tiles: BOTH global sides 256B-coalesced. pk4f8 packs 4 consecutive
// rows into one u32 (bit-identical numerics to per-element f2f8).
template <int R, int C>
__device__ __forceinline__ void transpose_body(const float* __restrict__ ip,
                                               u8* __restrict__ op,
                                               int bx, int by, int t,
                                               u32 (&tl)[64][65]) {
  const int r0 = by * 256, c0 = bx * 64;
  const int rg16 = t >> 4;      // 0..15
  const int cg = t & 15;        // 0..15 (group of 4 cols)
#pragma unroll
  for (int p = 0; p < 4; ++p) {
    const int rq = p * 16 + rg16;            // row-quad index 0..63 (rows rq*4..+3)
    const float* q = ip + (size_t)(r0 + rq * 4) * C + c0 + cg * 4;
    float4 v0 = *(const float4*)(q);
    float4 v1 = *(const float4*)(q + C);
    float4 v2 = *(const float4*)(q + 2 * C);
    float4 v3 = *(const float4*)(q + 3 * C);
    tl[cg * 4 + 0][rq] = pk4f8(v0.x, v1.x, v2.x, v3.x);
    tl[cg * 4 + 1][rq] = pk4f8(v0.y, v1.y, v2.y, v3.y);
    tl[cg * 4 + 2][rq] = pk4f8(v0.z, v1.z, v2.z, v3.z);
    tl[cg * 4 + 3][rq] = pk4f8(v0.w, v1.w, v2.w, v3.w);
  }
  __syncthreads();
  const int ch = t & 15;        // 16B chunk within the 256B output run
#pragma unroll
  for (int p = 0; p < 4; ++p) {
    const int c = p * 16 + (t >> 4);         // output row (= input col) 0..63
    uint4 w;
    w.x = tl[c][ch * 4 + 0];
    w.y = tl[c][ch * 4 + 1];
    w.z = tl[c][ch * 4 + 2];
    w.w = tl[c][ch * 4 + 3];
    *(uint4*)(op + (size_t)(c0 + c) * R + r0 + ch * 16) = w;
  }
}

#define NCAST (B_ * S_ * D_ / 1024)                 // 8192 blocks (256 thr x float4)
#define NT1 ((2 * H_ / 64) * (D_ / 256) * E_)       // 64*4*8 = 2048 blocks
#define NT2 ((D_ / 64) * (H_ / 256) * E_)           // 16*8*8 = 1024 blocks

__global__ void __launch_bounds__(256) prep_kernel(
    const float* __restrict__ x, const float* __restrict__ noise,
    const float* __restrict__ rw, const float* __restrict__ fiw,
    const float* __restrict__ fow,
    float* __restrict__ out_logits, float* __restrict__ out_probs,
    float* __restrict__ out_idx, float* __restrict__ out_w,
    int* __restrict__ ws_idx, float* __restrict__ ws_w,
    u32* __restrict__ xq, u8* __restrict__ wtin,
    u8* __restrict__ wtout) {
  __shared__ __align__(16) u32 tile[64][65];
  const int t = threadIdx.x;
  int bid = blockIdx.x;

  if (bid == 0) {  // -------- router (hidden under the memory-bound blocks) ------
    float* sl = (float*)&tile[0][0];
    float* sp = sl + 64;
    {
      const int pair = t >> 2, sub = t & 3;      // 64 (b,e) pairs x 4 threads
      const int b = pair >> 3, e = pair & 7;
      float acc = 0.f;
      const int d0 = sub * 64;
      for (int d = d0; d < d0 + 64; ++d)
        acc += noise[b * DN_ + d] * rw[d * E_ + e];
      acc += __shfl_xor(acc, 1);
      acc += __shfl_xor(acc, 2);
      if (sub == 0) sl[pair] = acc;
    }
    __syncthreads();
    if (t < 64) {
      const int b = t >> 3;
      float L = sl[t];
      out_logits[t] = L;
      float m = -1e30f;
      for (int j = 0; j < 8; ++j) m = fmaxf(m, sl[b * 8 + j]);
      float s = 0.f;
      for (int j = 0; j < 8; ++j) s += __expf(sl[b * 8 + j] - m);
      float p = __expf(L - m) / s;
      out_probs[t] = p;
      sp[t] = p;
    }
    __syncthreads();
    if (t < 64 && (t & 7) == 0) {
      const int b = t >> 3;
      int a1 = 0; float v1 = sp[b * 8];
      for (int j = 1; j < 8; ++j) { float v = sp[b * 8 + j]; if (v > v1) { v1 = v; a1 = j; } }
      int a2 = -1; float v2 = -1e30f;
      for (int j = 0; j < 8; ++j) {
        if (j == a1) continue;
        float v = sp[b * 8 + j]; if (v > v2) { v2 = v; a2 = j; }
      }
      float sum = fmaxf(v1 + v2, 1e-8f);
      float w1 = v1 / sum, w2 = v2 / sum;
      out_idx[b * 2] = (float)a1; out_idx[b * 2 + 1] = (float)a2;
      out_w[b * 2] = w1; out_w[b * 2 + 1] = w2;
      ws_idx[b * 2] = a1; ws_idx[b * 2 + 1] = a2;
      ws_w[b * 2] = w1; ws_w[b * 2 + 1] = w2;
    }
    return;
  }
  bid -= 1;
  if (bid < NCAST) {  // -------- cast x -> fp8 --------
    const size_t i = (size_t)bid * 256 + t;
    float4 v = *((const float4*)x + i);
    xq[i] = pk4f8(v.x, v.y, v.z, v.w);
    return;
  }
  bid -= NCAST;
  if (bid < NT1) {  // -------- fc_in_w [E][D][2H] f32 -> [E][2H][D] fp8 --------
    const int bx = bid & 63, by = (bid >> 6) & 3, e = bid >> 8;
    transpose_body<D_, 2 * H_>(fiw + (size_t)e * D_ * 2 * H_,
                               wtin + (size_t)e * D_ * 2 * H_, bx, by, t, tile);
    return;
  }
  bid -= NT1;
  {  // -------- fc_out_w [E][H][D] f32 -> [E][D][H] fp8 --------
    const int bx = bid & 15, by = (bid >> 4) & 7, e = bid >> 7;
    transpose_body<H_, D_>(fow + (size_t)e * H_ * D_,
                           wtout + (size_t)e * H_ * D_, bx, by, t, tile);
  }
}

// ---------------- GEMM1: hidden = silu-gated(x @ W_in + b_in) * coeff  (fp8) ----------
// Slot-merged: block computes BOTH experts of batch b over a shared A-tile.
// Tile: 128 s-rows x 64 hid-cols x {e0,e1} x {value,gate}; BK=128.
// 512 thr / 8 waves (2m x 4n): wave = 64 rows x 16 cols, acc 4i x 4(e,vg) = 64 AGPR.
// 512 MFMA per block-barrier (2x R4). LDS 48K -> 2 blocks/CU (16 waves, 50%).
// K-accumulation order per output element identical to R4 (ksub ascending).
__global__ void __launch_bounds__(512, 4) gemm1_kernel(
    const u8* __restrict__ xq,      // [B][S][D] fp8
    const u8* __restrict__ wtin,    // [E][2H][D] fp8 (pre-transposed)
    const float* __restrict__ bin,  // [E][2H] f32
    const int* __restrict__ ws_idx, const float* __restrict__ ws_w,
    u8* __restrict__ hid)           // [B*2][S][H] fp8
{
  const int nt = blockIdx.x;   // 32 tiles of 64 hid-cols
  const int mt = blockIdx.y;   // 8 s-tiles
  const int b  = blockIdx.z;   // 8
  const int e0 = ws_idx[b * 2] & 7, e1 = ws_idx[b * 2 + 1] & 7;
  const float c0 = ws_w[b * 2], c1 = ws_w[b * 2 + 1];

  __shared__ u8 As[128 * 128];   // 16 KB
  __shared__ u8 Bs[256 * 128];   // 32 KB: 64-row sections: e0v | e0g | e1v | e1g

  const int t = threadIdx.x;
  const int wave = t >> 6, lane = t & 63;
  const int wm = wave >> 2, wn = wave & 3;       // 2 x 4 wave grid
  const int lm = lane & 15, lq = lane >> 4;
  const int lrow8 = lane >> 3;                   // staging row within 8-row chunk
  const int kq = ((lane & 7) ^ lrow8) * 16;      // swizzled 16B-slot fetch offset
  const int fsw = lm & 7;                        // fragment-read row swizzle key
  const int p0 = lq >> 1, fb = (lq & 1) * 8;

  const u8* Ab  = xq + (size_t)b * (S_ * D_) + (size_t)mt * 128 * D_;
  const u8* Bv0 = wtin + (size_t)e0 * (2 * H_ * D_) + (size_t)nt * 64 * D_;
  const u8* Bg0 = Bv0 + (size_t)H_ * D_;
  const u8* Bv1 = wtin + (size_t)e1 * (2 * H_ * D_) + (size_t)nt * 64 * D_;
  const u8* Bg1 = Bv1 + (size_t)H_ * D_;

  const f32x4 vz = {0.f, 0.f, 0.f, 0.f};
  f32x4 acc[4][4];   // [i][ e0v, e0g, e1v, e1g ]
#pragma unroll
  for (int i = 0; i < 4; ++i)
#pragma unroll
    for (int j = 0; j < 4; ++j) acc[i][j] = vz;

  for (int kt = 0; kt < D_ / 128; ++kt) {        // 8 k-iters
    const int k0 = kt * 128 + kq;
    const size_t rr = (size_t)(wave * 8 + lrow8);
    // A: 16 chunks of 8 rows; wave stages chunks w and w+8
    gll16(Ab + rr * D_ + k0, (char*)As + wave * 1024);
    gll16(Ab + (rr + 64) * D_ + k0, (char*)As + (wave + 8) * 1024);
    // B: 4 sections of 64 rows = 8 chunks each; wave stages chunk w of each section
    gll16(Bv0 + rr * D_ + k0, (char*)Bs + wave * 1024);
    gll16(Bg0 + rr * D_ + k0, (char*)Bs + (8 + wave) * 1024);
    gll16(Bv1 + rr * D_ + k0, (char*)Bs + (16 + wave) * 1024);
    gll16(Bg1 + rr * D_ + k0, (char*)Bs + (24 + wave) * 1024);
    __syncthreads();
#pragma unroll
    for (int ks = 0; ks < 4; ++ks) {             // 4 k-substeps of 32
      const int pw = ((ks * 2 + p0) ^ fsw) * 16 + fb;
      ll af[4];
#pragma unroll
      for (int i = 0; i < 4; ++i)
        af[i] = *(const ll*)(As + (wm * 64 + i * 16 + lm) * 128 + pw);
      const int brow = wn * 16 + lm;
      ll b0v = *(const ll*)(Bs + (brow) * 128 + pw);
      ll b0g = *(const ll*)(Bs + (64 + brow) * 128 + pw);
      ll b1v = *(const ll*)(Bs + (128 + brow) * 128 + pw);
      ll b1g = *(const ll*)(Bs + (192 + brow) * 128 + pw);
#pragma unroll
      for (int i = 0; i < 4; ++i) {
        acc[i][0] = __builtin_amdgcn_mfma_f32_16x16x32_fp8_fp8(af[i], b0v, acc[i][0], 0, 0, 0);
        acc[i][1] = __builtin_amdgcn_mfma_f32_16x16x32_fp8_fp8(af[i], b0g, acc[i][1], 0, 0, 0);
        acc[i][2] = __builtin_amdgcn_mfma_f32_16x16x32_fp8_fp8(af[i], b1v, acc[i][2], 0, 0, 0);
        acc[i][3] = __builtin_amdgcn_mfma_f32_16x16x32_fp8_fp8(af[i], b1g, acc[i][3], 0, 0, 0);
      }
    }
    __syncthreads();
  }

  u8* hb0 = hid + (size_t)(b * 2 + 0) * (S_ * H_);
  u8* hb1 = hid + (size_t)(b * 2 + 1) * (S_ * H_);
  const int row0 = mt * 128 + wm * 64;
  const int col = nt * 64 + wn * 16 + lm;
  const float bv0 = bin[e0 * 2 * H_ + col];
  const float bg0 = bin[e0 * 2 * H_ + H_ + col];
  const float bv1 = bin[e1 * 2 * H_ + col];
  const float bg1 = bin[e1 * 2 * H_ + H_ + col];
#pragma unroll
  for (int i = 0; i < 4; ++i) {
#pragma unroll
    for (int r = 0; r < 4; ++r) {
      const int srow = row0 + i * 16 + lq * 4 + r;
      float v0 = acc[i][0][r] + bv0;
      float g0 = acc[i][1][r] + bg0;
      hb0[(size_t)srow * H_ + col] = f2f8(v0 * g0 / (1.f + __expf(-g0)) * c0);
      float v1 = acc[i][2][r] + bv1;
      float g1 = acc[i][3][r] + bg1;
      hb1[(size_t)srow * H_ + col] = f2f8(v1 * g1 / (1.f + __expf(-g1)) * c1);
    }
  }
}

// ---------------- GEMM2: mixed[b] = sum_slots hidden[b,slot] @ W_out[e] + bias (fp8) ---
// 128x128 tiles, BK=128, 512 thr / 8 waves (2m x 4n): wave = 64 rows x 32 cols,
// acc 4x2 = 32 AGPR; 256 MFMA per block-barrier (2x R4). Grid 8x8x8 = 512 blocks,
// all-resident. Slot loop flattened (32 K-steps).
__global__ void __launch_bounds__(512, 4) gemm2_kernel(
    const u8* __restrict__ hid,     // [B*2][S][H] fp8 (coeff pre-applied)
    const u8* __restrict__ wtout,   // [E][D][H] fp8 (pre-transposed)
    const float* __restrict__ bout, // [E][D] f32
    const int* __restrict__ ws_idx, const float* __restrict__ ws_w,
    float* __restrict__ out)        // [B][S][D] f32
{
  const int nt = blockIdx.x;  // 8 d-tiles of 128
  const int mt = blockIdx.y;  // 8 s-tiles of 128
  const int b  = blockIdx.z;  // 8

  __shared__ u8 As[128 * 128];  // 16 KB
  __shared__ u8 Bs[128 * 128];  // 16 KB

  const int t = threadIdx.x;
  const int wave = t >> 6, lane = t & 63;
  const int wm = wave >> 2, wn = wave & 3;
  const int lm = lane & 15, lq = lane >> 4;
  const int lrow8 = lane >> 3;
  const int kq = ((lane & 7) ^ lrow8) * 16;
  const int fsw = lm & 7;
  const int p0 = lq >> 1, fb = (lq & 1) * 8;

  const int e0 = ws_idx[b * 2] & 7, e1 = ws_idx[b * 2 + 1] & 7;
  const u8* Ab0 = hid + ((size_t)(b * 2 + 0) * S_ + mt * 128) * H_;
  const u8* Ab1 = hid + ((size_t)(b * 2 + 1) * S_ + mt * 128) * H_;
  const u8* Bb0 = wtout + ((size_t)e0 * D_ + nt * 128) * H_;
  const u8* Bb1 = wtout + ((size_t)e1 * D_ + nt * 128) * H_;

  const f32x4 vz = {0.f, 0.f, 0.f, 0.f};
  f32x4 acc[4][2];
#pragma unroll
  for (int i = 0; i < 4; ++i)
#pragma unroll
    for (int j = 0; j < 2; ++j) acc[i][j] = vz;

  for (int it = 0; it < 32; ++it) {              // 2 slots x 16 k-iters
    const u8* Ab = (it & 16) ? Ab1 : Ab0;
    const u8* Bb = (it & 16) ? Bb1 : Bb0;
    const int k0 = (it & 15) * 128 + kq;
    const size_t rr = (size_t)(wave * 8 + lrow8);
    gll16(Ab + rr * H_ + k0, (char*)As + wave * 1024);
    gll16(Ab + (rr + 64) * H_ + k0, (char*)As + (wave + 8) * 1024);
    gll16(Bb + rr * H_ + k0, (char*)Bs + wave * 1024);
    gll16(Bb + (rr + 64) * H_ + k0, (char*)Bs + (wave + 8) * 1024);
    __syncthreads();
#pragma unroll
    for (int ks = 0; ks < 4; ++ks) {
      const int pw = ((ks * 2 + p0) ^ fsw) * 16 + fb;
      ll af[4], bf[2];
#pragma unroll
      for (int i = 0; i < 4; ++i)
        af[i] = *(const ll*)(As + (wm * 64 + i * 16 + lm) * 128 + pw);
#pragma unroll
      for (int j = 0; j < 2; ++j)
        bf[j] = *(const ll*)(Bs + (wn * 32 + j * 16 + lm) * 128 + pw);
#pragma unroll
      for (int i = 0; i < 4; ++i)
#pragma unroll
        for (int j = 0; j < 2; ++j)
          acc[i][j] = __builtin_amdgcn_mfma_f32_16x16x32_fp8_fp8(af[i], bf[j], acc[i][j], 0, 0, 0);
    }
    __syncthreads();
  }

  const float c0 = ws_w[b * 2], c1 = ws_w[b * 2 + 1];
  float* ob = out + (size_t)b * (S_ * D_);
  const int row0 = mt * 128 + wm * 64;
  const int col0 = nt * 128 + wn * 32;
#pragma unroll
  for (int j = 0; j < 2; ++j) {
    const int col = col0 + j * 16 + lm;
    const float bias = c0 * bout[e0 * D_ + col] + c1 * bout[e1 * D_ + col];
#pragma unroll
    for (int i = 0; i < 4; ++i)
#pragma unroll
      for (int r = 0; r < 4; ++r)
        ob[(size_t)(row0 + i * 16 + lq * 4 + r) * D_ + col] = acc[i][j][r] + bias;
  }
}

extern "C" void kernel_launch(void* const* d_in, const int* in_sizes, int n_in,
                              void* d_out, int out_size, void* d_ws, size_t ws_size,
                              hipStream_t stream) {
  const float* x     = (const float*)d_in[0];
  const float* noise = (const float*)d_in[1];
  const float* rw    = (const float*)d_in[2];
  const float* fiw   = (const float*)d_in[3];
  const float* fib   = (const float*)d_in[4];
  const float* fow   = (const float*)d_in[5];
  const float* fob   = (const float*)d_in[6];
  float* out = (float*)d_out;

  char* ws = (char*)d_ws;
  int*   ws_idx = (int*)ws;                                 // 16 ints
  float* ws_w   = (float*)(ws + 64);                        // 16 floats
  u8* xq    = (u8*)(ws + 256);                              // [B][S][D] fp8 (8 MB)
  u8* wtin  = xq + (size_t)B_ * S_ * D_;                    // [E][2H][D] fp8 (32 MB)
  u8* wtout = wtin + (size_t)E_ * 2 * H_ * D_;              // [E][D][H] fp8 (16 MB)
  u8* hid   = wtout + (size_t)E_ * D_ * H_;                 // [B*2][S][H] fp8 (32 MB)

  float* out_mixed  = out;
  float* out_logits = out + (size_t)B_ * S_ * D_;
  float* out_probs  = out_logits + B_ * E_;
  float* out_idx    = out_probs + B_ * E_;
  float* out_w      = out_idx + B_ * 2;

  prep_kernel<<<1 + NCAST + NT1 + NT2, 256, 0, stream>>>(
      x, noise, rw, fiw, fow, out_logits, out_probs, out_idx, out_w,
      ws_idx, ws_w, (u32*)xq, wtin, wtout);
  gemm1_kernel<<<dim3(32, 8, 8), 512, 0, stream>>>(xq, wtin, fib, ws_idx, ws_w, hid);
  gemm2_kernel<<<dim3(8, 8, 8), 512, 0, stream>>>(hid, wtout, fob, ws_idx, ws_w, out_mixed);
}

// Round 6
// 396.533 us; speedup vs baseline: 1.1256x; 1.1256x over previous
//
#include <hip/hip_runtime.h>
#include <stdint.h>

#define B_ 8
#define S_ 1024
#define D_ 1024
#define H_ 2048
#define E_ 8
#define DN_ 256

typedef unsigned char u8;
typedef unsigned int u32;
typedef long long ll;
typedef int i32x4 __attribute__((ext_vector_type(4)));
typedef int i32x8 __attribute__((ext_vector_type(8)));
typedef float f32x16 __attribute__((ext_vector_type(16)));

// fp8 e4m3 (OCP on gfx950) converts
__device__ __forceinline__ u8 f2f8(float f) {
  return (u8)(__builtin_amdgcn_cvt_pk_fp8_f32(f, f, 0, false) & 0xff);
}
__device__ __forceinline__ u32 pk4f8(float a, float b, float c, float d) {
  int w = __builtin_amdgcn_cvt_pk_fp8_f32(a, b, 0, false);
  w = __builtin_amdgcn_cvt_pk_fp8_f32(c, d, w, true);
  return (u32)w;
}

// async global->LDS, 16B per lane. LDS dest is wave-uniform base; HW adds lane*16.
__device__ __forceinline__ void gll16(const void* g, void* l) {
  __builtin_amdgcn_global_load_lds(
      (__attribute__((address_space(1))) void*)g,
      (__attribute__((address_space(3))) void*)l, 16, 0, 0);
}

// MX-scaled fp8 MFMA with unit scales (e8m0 0x7f = 2^0): plain fp8 GEMM at 2x rate.
// cbsz=0 (A fmt = FP8 e4m3), blgp=0 (B fmt = FP8 e4m3); all scale bytes 0x7f.
#define MFMA_MX(a, b, c) \
  __builtin_amdgcn_mfma_scale_f32_32x32x64_f8f6f4((a), (b), (c), 0, 0, 0, 0x7f7f7f7f, 0, 0x7f7f7f7f)

// 32B A/B fragment read: two XOR-swizzled 16B slots (sb, sb+1) from a 128B LDS row.
__device__ __forceinline__ i32x8 ldf(const u8* base, int rowoff, int sb, int f) {
  i32x4 lo = *(const i32x4*)(base + rowoff + ((sb ^ f) << 4));
  i32x4 hi = *(const i32x4*)(base + rowoff + (((sb + 1) ^ f) << 4));
  return __builtin_shufflevector(lo, hi, 0, 1, 2, 3, 4, 5, 6, 7);
}

// ---------------- merged prep: router + cast x + transpose/cast weights ----------------
template <int R, int C>
__device__ __forceinline__ void transpose_body(const float* __restrict__ ip,
                                               u8* __restrict__ op,
                                               int bx, int by, int t,
                                               u32 (&tl)[64][65]) {
  const int r0 = by * 256, c0 = bx * 64;
  const int rg16 = t >> 4;
  const int cg = t & 15;
#pragma unroll
  for (int p = 0; p < 4; ++p) {
    const int rq = p * 16 + rg16;
    const float* q = ip + (size_t)(r0 + rq * 4) * C + c0 + cg * 4;
    float4 v0 = *(const float4*)(q);
    float4 v1 = *(const float4*)(q + C);
    float4 v2 = *(const float4*)(q + 2 * C);
    float4 v3 = *(const float4*)(q + 3 * C);
    tl[cg * 4 + 0][rq] = pk4f8(v0.x, v1.x, v2.x, v3.x);
    tl[cg * 4 + 1][rq] = pk4f8(v0.y, v1.y, v2.y, v3.y);
    tl[cg * 4 + 2][rq] = pk4f8(v0.z, v1.z, v2.z, v3.z);
    tl[cg * 4 + 3][rq] = pk4f8(v0.w, v1.w, v2.w, v3.w);
  }
  __syncthreads();
  const int ch = t & 15;
#pragma unroll
  for (int p = 0; p < 4; ++p) {
    const int c = p * 16 + (t >> 4);
    uint4 w;
    w.x = tl[c][ch * 4 + 0];
    w.y = tl[c][ch * 4 + 1];
    w.z = tl[c][ch * 4 + 2];
    w.w = tl[c][ch * 4 + 3];
    *(uint4*)(op + (size_t)(c0 + c) * R + r0 + ch * 16) = w;
  }
}

#define NCAST (B_ * S_ * D_ / 1024)
#define NT1 ((2 * H_ / 64) * (D_ / 256) * E_)
#define NT2 ((D_ / 64) * (H_ / 256) * E_)

__global__ void __launch_bounds__(256) prep_kernel(
    const float* __restrict__ x, const float* __restrict__ noise,
    const float* __restrict__ rw, const float* __restrict__ fiw,
    const float* __restrict__ fow,
    float* __restrict__ out_logits, float* __restrict__ out_probs,
    float* __restrict__ out_idx, float* __restrict__ out_w,
    int* __restrict__ ws_idx, float* __restrict__ ws_w,
    u32* __restrict__ xq, u8* __restrict__ wtin,
    u8* __restrict__ wtout) {
  __shared__ __align__(16) u32 tile[64][65];
  const int t = threadIdx.x;
  int bid = blockIdx.x;

  if (bid == 0) {  // -------- router --------
    float* sl = (float*)&tile[0][0];
    float* sp = sl + 64;
    {
      const int pair = t >> 2, sub = t & 3;
      const int b = pair >> 3, e = pair & 7;
      float acc = 0.f;
      const int d0 = sub * 64;
      for (int d = d0; d < d0 + 64; ++d)
        acc += noise[b * DN_ + d] * rw[d * E_ + e];
      acc += __shfl_xor(acc, 1);
      acc += __shfl_xor(acc, 2);
      if (sub == 0) sl[pair] = acc;
    }
    __syncthreads();
    if (t < 64) {
      const int b = t >> 3;
      float L = sl[t];
      out_logits[t] = L;
      float m = -1e30f;
      for (int j = 0; j < 8; ++j) m = fmaxf(m, sl[b * 8 + j]);
      float s = 0.f;
      for (int j = 0; j < 8; ++j) s += __expf(sl[b * 8 + j] - m);
      float p = __expf(L - m) / s;
      out_probs[t] = p;
      sp[t] = p;
    }
    __syncthreads();
    if (t < 64 && (t & 7) == 0) {
      const int b = t >> 3;
      int a1 = 0; float v1 = sp[b * 8];
      for (int j = 1; j < 8; ++j) { float v = sp[b * 8 + j]; if (v > v1) { v1 = v; a1 = j; } }
      int a2 = -1; float v2 = -1e30f;
      for (int j = 0; j < 8; ++j) {
        if (j == a1) continue;
        float v = sp[b * 8 + j]; if (v > v2) { v2 = v; a2 = j; }
      }
      float sum = fmaxf(v1 + v2, 1e-8f);
      float w1 = v1 / sum, w2 = v2 / sum;
      out_idx[b * 2] = (float)a1; out_idx[b * 2 + 1] = (float)a2;
      out_w[b * 2] = w1; out_w[b * 2 + 1] = w2;
      ws_idx[b * 2] = a1; ws_idx[b * 2 + 1] = a2;
      ws_w[b * 2] = w1; ws_w[b * 2 + 1] = w2;
    }
    return;
  }
  bid -= 1;
  if (bid < NCAST) {  // -------- cast x -> fp8 --------
    const size_t i = (size_t)bid * 256 + t;
    float4 v = *((const float4*)x + i);
    xq[i] = pk4f8(v.x, v.y, v.z, v.w);
    return;
  }
  bid -= NCAST;
  if (bid < NT1) {  // -------- fc_in_w -> [E][2H][D] fp8 --------
    const int bx = bid & 63, by = (bid >> 6) & 3, e = bid >> 8;
    transpose_body<D_, 2 * H_>(fiw + (size_t)e * D_ * 2 * H_,
                               wtin + (size_t)e * D_ * 2 * H_, bx, by, t, tile);
    return;
  }
  bid -= NT1;
  {  // -------- fc_out_w -> [E][D][H] fp8 --------
    const int bx = bid & 15, by = (bid >> 4) & 7, e = bid >> 7;
    transpose_body<H_, D_>(fow + (size_t)e * H_ * D_,
                           wtout + (size_t)e * H_ * D_, bx, by, t, tile);
  }
}

// ---------------- GEMM1: hidden = silu-gated(x @ W_in + b_in) * coeff  (MX fp8) -------
// R4 structure (128x64 tile, BK=128, 256 thr, one slot/block, 2-barrier loop, same
// staging+swizzle) with compute switched to mfma_scale 32x32x64 @ unit scales:
// 2x MFMA rate, 1/4 instruction count. Wave = 64 rows x 32 cols = 2x1 32x32 tiles
// x {v,g}: acc 4 x f32x16 = 64 AGPR (same as R4's budget).
__global__ void __launch_bounds__(256, 4) gemm1_kernel(
    const u8* __restrict__ xq,      // [B][S][D] fp8
    const u8* __restrict__ wtin,    // [E][2H][D] fp8 (pre-transposed)
    const float* __restrict__ bin,  // [E][2H] f32
    const int* __restrict__ ws_idx, const float* __restrict__ ws_w,
    u8* __restrict__ hid)           // [B*2][S][H] fp8
{
  const int nt = blockIdx.x;   // 32 tiles of 64 hid-cols
  const int mt = blockIdx.y;   // 8 s-tiles
  const int z  = blockIdx.z;   // 16 = b*2+slot
  const int b  = z >> 1;
  const int e  = ws_idx[z] & 7;
  const float csc = ws_w[z];

  __shared__ u8 As[128 * 128];   // 16 KB
  __shared__ u8 Bs[128 * 128];   // 16 KB: rows 0-63 value, 64-127 gate

  const int t = threadIdx.x;
  const int wave = t >> 6, lane = t & 63;
  const int wm = wave >> 1, wn = wave & 1;
  const int l31 = lane & 31, lh = lane >> 5, f = lane & 7;
  const int lrow8 = lane >> 3;
  const int kq = ((lane & 7) ^ lrow8) * 16;

  const u8* Ab  = xq + (size_t)b * (S_ * D_) + (size_t)mt * 128 * D_;
  const u8* Bvb = wtin + (size_t)e * (2 * H_ * D_) + (size_t)nt * 64 * D_;
  const u8* Bgb = Bvb + (size_t)H_ * D_;

  f32x16 accv[2], accg[2];
#pragma unroll
  for (int i = 0; i < 16; ++i) {
    accv[0][i] = 0.f; accv[1][i] = 0.f; accg[0][i] = 0.f; accg[1][i] = 0.f;
  }

  for (int kt = 0; kt < D_ / 128; ++kt) {        // 8 k-iters
    const int k0 = kt * 128 + kq;
    gll16(Ab + (size_t)(wave * 8 + lrow8) * D_ + k0, (char*)As + wave * 1024);
    gll16(Ab + (size_t)((wave + 4) * 8 + lrow8) * D_ + k0, (char*)As + (wave + 4) * 1024);
    gll16(Ab + (size_t)((wave + 8) * 8 + lrow8) * D_ + k0, (char*)As + (wave + 8) * 1024);
    gll16(Ab + (size_t)((wave + 12) * 8 + lrow8) * D_ + k0, (char*)As + (wave + 12) * 1024);
    gll16(Bvb + (size_t)(wave * 8 + lrow8) * D_ + k0, (char*)Bs + wave * 1024);
    gll16(Bvb + (size_t)((wave + 4) * 8 + lrow8) * D_ + k0, (char*)Bs + (wave + 4) * 1024);
    gll16(Bgb + (size_t)(wave * 8 + lrow8) * D_ + k0, (char*)Bs + (8 + wave) * 1024);
    gll16(Bgb + (size_t)((wave + 4) * 8 + lrow8) * D_ + k0, (char*)Bs + (12 + wave) * 1024);
    __syncthreads();
#pragma unroll
    for (int km = 0; km < 2; ++km) {             // two K=64 halves
      const int sb = km * 4 + lh * 2;
      i32x8 a0 = ldf(As, (wm * 64 + l31) * 128, sb, f);
      i32x8 a1 = ldf(As, (wm * 64 + 32 + l31) * 128, sb, f);
      i32x8 bv = ldf(Bs, (wn * 32 + l31) * 128, sb, f);
      i32x8 bg = ldf(Bs, (64 + wn * 32 + l31) * 128, sb, f);
      accv[0] = MFMA_MX(a0, bv, accv[0]);
      accg[0] = MFMA_MX(a0, bg, accg[0]);
      accv[1] = MFMA_MX(a1, bv, accv[1]);
      accg[1] = MFMA_MX(a1, bg, accg[1]);
    }
    __syncthreads();
  }

  u8* hb = hid + (size_t)z * (S_ * H_);
  const int row0 = mt * 128 + wm * 64;
  const int col = nt * 64 + wn * 32 + l31;
  const float bvx = bin[e * 2 * H_ + col];
  const float bgx = bin[e * 2 * H_ + H_ + col];
#pragma unroll
  for (int i = 0; i < 2; ++i) {
#pragma unroll
    for (int r = 0; r < 16; ++r) {
      // C/D 32x32 layout: col=lane&31, row=(r&3)+8*(r>>2)+4*(lane>>5)
      const int srow = row0 + i * 32 + (r & 3) + 8 * (r >> 2) + 4 * lh;
      float v = accv[i][r] + bvx;
      float g = accg[i][r] + bgx;
      hb[(size_t)srow * H_ + col] = f2f8(v * g / (1.f + __expf(-g)) * csc);
    }
  }
}

// ---------------- GEMM2: mixed[b] = sum_slots hidden[b,slot] @ W_out[e] + bias --------
// R4 structure (128x64 tile, BK=128, 256 thr, slot-flattened 32 K-steps) with MX
// compute. Wave = 64 rows x 32 cols: acc 2 x f32x16 = 32 AGPR.
__global__ void __launch_bounds__(256, 4) gemm2_kernel(
    const u8* __restrict__ hid,     // [B*2][S][H] fp8 (coeff pre-applied)
    const u8* __restrict__ wtout,   // [E][D][H] fp8 (pre-transposed)
    const float* __restrict__ bout, // [E][D] f32
    const int* __restrict__ ws_idx, const float* __restrict__ ws_w,
    float* __restrict__ out)        // [B][S][D] f32
{
  const int nt = blockIdx.x;  // 16 d-tiles of 64
  const int mt = blockIdx.y;  // 8 s-tiles of 128
  const int b  = blockIdx.z;  // 8

  __shared__ u8 As[128 * 128];  // 16 KB
  __shared__ u8 Bs[64 * 128];   // 8 KB

  const int t = threadIdx.x;
  const int wave = t >> 6, lane = t & 63;
  const int wm = wave >> 1, wn = wave & 1;
  const int l31 = lane & 31, lh = lane >> 5, f = lane & 7;
  const int lrow8 = lane >> 3;
  const int kq = ((lane & 7) ^ lrow8) * 16;

  const int e0 = ws_idx[b * 2] & 7, e1 = ws_idx[b * 2 + 1] & 7;
  const u8* Ab0 = hid + ((size_t)(b * 2 + 0) * S_ + mt * 128) * H_;
  const u8* Ab1 = hid + ((size_t)(b * 2 + 1) * S_ + mt * 128) * H_;
  const u8* Bb0 = wtout + ((size_t)e0 * D_ + nt * 64) * H_;
  const u8* Bb1 = wtout + ((size_t)e1 * D_ + nt * 64) * H_;

  f32x16 acc[2];
#pragma unroll
  for (int i = 0; i < 16; ++i) { acc[0][i] = 0.f; acc[1][i] = 0.f; }

  for (int it = 0; it < 32; ++it) {              // 2 slots x 16 k-iters
    const u8* Ab = (it & 16) ? Ab1 : Ab0;
    const u8* Bb = (it & 16) ? Bb1 : Bb0;
    const int k0 = (it & 15) * 128 + kq;
    gll16(Ab + (size_t)(wave * 8 + lrow8) * H_ + k0, (char*)As + wave * 1024);
    gll16(Ab + (size_t)((wave + 4) * 8 + lrow8) * H_ + k0, (char*)As + (wave + 4) * 1024);
    gll16(Ab + (size_t)((wave + 8) * 8 + lrow8) * H_ + k0, (char*)As + (wave + 8) * 1024);
    gll16(Ab + (size_t)((wave + 12) * 8 + lrow8) * H_ + k0, (char*)As + (wave + 12) * 1024);
    gll16(Bb + (size_t)(wave * 8 + lrow8) * H_ + k0, (char*)Bs + wave * 1024);
    gll16(Bb + (size_t)((wave + 4) * 8 + lrow8) * H_ + k0, (char*)Bs + (wave + 4) * 1024);
    __syncthreads();
#pragma unroll
    for (int km = 0; km < 2; ++km) {
      const int sb = km * 4 + lh * 2;
      i32x8 a0 = ldf(As, (wm * 64 + l31) * 128, sb, f);
      i32x8 a1 = ldf(As, (wm * 64 + 32 + l31) * 128, sb, f);
      i32x8 bf = ldf(Bs, (wn * 32 + l31) * 128, sb, f);
      acc[0] = MFMA_MX(a0, bf, acc[0]);
      acc[1] = MFMA_MX(a1, bf, acc[1]);
    }
    __syncthreads();
  }

  const float c0 = ws_w[b * 2], c1 = ws_w[b * 2 + 1];
  float* ob = out + (size_t)b * (S_ * D_);
  const int row0 = mt * 128 + wm * 64;
  const int col = nt * 64 + wn * 32 + l31;
  const float bias = c0 * bout[e0 * D_ + col] + c1 * bout[e1 * D_ + col];
#pragma unroll
  for (int i = 0; i < 2; ++i) {
#pragma unroll
    for (int r = 0; r < 16; ++r) {
      const int srow = row0 + i * 32 + (r & 3) + 8 * (r >> 2) + 4 * lh;
      ob[(size_t)srow * D_ + col] = acc[i][r] + bias;
    }
  }
}

extern "C" void kernel_launch(void* const* d_in, const int* in_sizes, int n_in,
                              void* d_out, int out_size, void* d_ws, size_t ws_size,
                              hipStream_t stream) {
  const float* x     = (const float*)d_in[0];
  const float* noise = (const float*)d_in[1];
  const float* rw    = (const float*)d_in[2];
  const float* fiw   = (const float*)d_in[3];
  const float* fib   = (const float*)d_in[4];
  const float* fow   = (const float*)d_in[5];
  const float* fob   = (const float*)d_in[6];
  float* out = (float*)d_out;

  char* ws = (char*)d_ws;
  int*   ws_idx = (int*)ws;                                 // 16 ints
  float* ws_w   = (float*)(ws + 64);                        // 16 floats
  u8* xq    = (u8*)(ws + 256);                              // [B][S][D] fp8 (8 MB)
  u8* wtin  = xq + (size_t)B_ * S_ * D_;                    // [E][2H][D] fp8 (32 MB)
  u8* wtout = wtin + (size_t)E_ * 2 * H_ * D_;              // [E][D][H] fp8 (16 MB)
  u8* hid   = wtout + (size_t)E_ * D_ * H_;                 // [B*2][S][H] fp8 (32 MB)

  float* out_mixed  = out;
  float* out_logits = out + (size_t)B_ * S_ * D_;
  float* out_probs  = out_logits + B_ * E_;
  float* out_idx    = out_probs + B_ * E_;
  float* out_w      = out_idx + B_ * 2;

  prep_kernel<<<1 + NCAST + NT1 + NT2, 256, 0, stream>>>(
      x, noise, rw, fiw, fow, out_logits, out_probs, out_idx, out_w,
      ws_idx, ws_w, (u32*)xq, wtin, wtout);
  gemm1_kernel<<<dim3(32, 8, 16), 256, 0, stream>>>(xq, wtin, fib, ws_idx, ws_w, hid);
  gemm2_kernel<<<dim3(16, 8, 8), 256, 0, stream>>>(hid, wtout, fob, ws_idx, ws_w, out_mixed);
}